// Round 1
// baseline (125.540 us; speedup 1.0000x reference)
//
#include <hip/hip_runtime.h>

// ConvCaps (Matrix Capsules w/ EM routing), MI355X fp32 implementation.
// One block per output position (b, oi, oj): 784 blocks x 256 threads.
// Votes are recomputed per pass (3 passes for iters=2) from LDS poses +
// L2-resident weights; per-class stats reduced with intra-wave shuffles.

namespace {

constexpr int OHW  = 14;
constexpr int NPOS = 4 * OHW * OHW;     // 784
constexpr int NN   = 144;               // K*K*B = 3*3*16
constexpr int CC   = 32;
constexpr float LAMB  = 0.01f;
constexpr float EPSF  = 1e-6f;
constexpr float LN2PI = 1.8378770664093453f;
constexpr int RS = 33;                  // padded leading dim for r (bank-conflict-free column access)

__device__ __forceinline__ void mat44(const float4 pr[4], const float4 wr[4], float v[16]) {
  #pragma unroll
  for (int i = 0; i < 4; ++i) {
    v[4*i+0] = fmaf(pr[i].x, wr[0].x, fmaf(pr[i].y, wr[1].x, fmaf(pr[i].z, wr[2].x, pr[i].w * wr[3].x)));
    v[4*i+1] = fmaf(pr[i].x, wr[0].y, fmaf(pr[i].y, wr[1].y, fmaf(pr[i].z, wr[2].y, pr[i].w * wr[3].y)));
    v[4*i+2] = fmaf(pr[i].x, wr[0].z, fmaf(pr[i].y, wr[1].z, fmaf(pr[i].z, wr[2].z, pr[i].w * wr[3].z)));
    v[4*i+3] = fmaf(pr[i].x, wr[0].w, fmaf(pr[i].y, wr[1].w, fmaf(pr[i].z, wr[2].w, pr[i].w * wr[3].w)));
  }
}

__global__ __launch_bounds__(256)
void convcaps_em(const float* __restrict__ x,
                 const float* __restrict__ a,
                 const float* __restrict__ w,        // (144, 32, 4, 4)
                 const float* __restrict__ beta_u,   // (32,1)
                 const float* __restrict__ beta_a,   // (32,1)
                 const int*   __restrict__ iters_p,
                 float* __restrict__ out_mu,         // (4,14,14,32,16)
                 float* __restrict__ out_a)          // (4,14,14,32,1)
{
  __shared__ __align__(16) float sP[NN * 16];   // pose patch, row n = 4x4 matrix row-major
  __shared__ float sA[NN];                      // input activations
  __shared__ float sR[NN * RS];                 // r[n][c] (and temporarily ln_ap)

  const int tid = threadIdx.x;
  const int pos = blockIdx.x;
  const int b   = pos / (OHW * OHW);
  const int rem = pos - b * (OHW * OHW);
  const int oi  = rem / OHW;
  const int oj  = rem - oi * OHW;

  int iters = iters_p[0];
  iters = (iters < 1) ? 1 : (iters > 16 ? 16 : iters);

  // ---- stage pose patch + activations ----
  // n = (kh*3+kw)*16 + bc maps to x[b, oi+kh, oj+kw, bc, :]
  #pragma unroll
  for (int t = 0; t < 9; ++t) {
    const int kh = t / 3, kw = t % 3;
    sP[t * 256 + tid] = x[(((b * 16 + oi + kh) * 16) + (oj + kw)) * 256 + tid];
  }
  if (tid < NN) {
    const int kh = tid / 48, kw = (tid >> 4) % 3, bc = tid & 15;
    sA[tid] = a[(((b * 16 + oi + kh) * 16) + (oj + kw)) * 16 + bc];
  }
  __syncthreads();
  #pragma unroll
  for (int t = 0; t < 18; ++t) {
    const int idx = t * 256 + tid;          // 0..4607
    const int n = idx >> 5, c = idx & 31;
    sR[n * RS + c] = sA[n] * (1.0f / CC);
  }
  __syncthreads();

  // thread map: octets of consecutive lanes own consecutive classes;
  // sub (n-slice) lives in lane bits 3..5 so reduction is shfl_xor 8/16/32.
  const int lane = tid & 63;
  const int wv   = tid >> 6;
  const int c    = wv * 8 + (lane & 7);     // 0..31
  const int sub  = lane >> 3;               // 0..7
  const float bu = beta_u[c];
  const float ba = beta_a[c];

  float mu[16], hi[16];

  for (int it = 0; it < iters; ++it) {
    // ---- r_sum over n for this class ----
    float rs = 0.f;
    #pragma unroll
    for (int k = 0; k < 18; ++k) rs += sR[(sub + 8 * k) * RS + c];
    rs += __shfl_xor(rs, 8);
    rs += __shfl_xor(rs, 16);
    rs += __shfl_xor(rs, 32);
    const float inv = 1.0f / (rs + EPSF);

    // ---- M-step accumulate S0/S1/S2 over this thread's n slice ----
    float S0 = 0.f, S1[16], S2[16];
    #pragma unroll
    for (int p = 0; p < 16; ++p) { S1[p] = 0.f; S2[p] = 0.f; }

    for (int k = 0; k < 18; ++k) {
      const int n = sub + 8 * k;
      const float coeff = sR[n * RS + c] * inv;
      const float4* Pp = (const float4*)(sP + n * 16);
      const float4 pr[4] = {Pp[0], Pp[1], Pp[2], Pp[3]};
      const float4* Wp = (const float4*)(w + n * 512 + c * 16);
      const float4 wr[4] = {Wp[0], Wp[1], Wp[2], Wp[3]};
      float v[16];
      mat44(pr, wr, v);
      S0 += coeff;
      #pragma unroll
      for (int p = 0; p < 16; ++p) {
        S1[p] = fmaf(coeff, v[p], S1[p]);
        S2[p] = fmaf(coeff * v[p], v[p], S2[p]);
      }
    }
    // ---- reduce over the 8 sub-lanes (all lanes keep full sums) ----
    #pragma unroll
    for (int m = 8; m <= 32; m <<= 1) {
      S0 += __shfl_xor(S0, m);
      #pragma unroll
      for (int p = 0; p < 16; ++p) {
        S1[p] += __shfl_xor(S1[p], m);
        S2[p] += __shfl_xor(S2[p], m);
      }
    }

    // ---- per-class stats: mu, sigma^2, a_out (redundant across sub-lanes) ----
    float logsum = 0.f;
    #pragma unroll
    for (int p = 0; p < 16; ++p) {
      mu[p] = S1[p];
      float sig = S2[p] - mu[p] * (2.0f * S1[p] - mu[p] * S0) + EPSF;  // = sum coeff*(v-mu)^2 + eps
      sig = fmaxf(sig, 1e-12f);
      logsum += __logf(sig);
      hi[p] = 0.5f / sig;
    }
    const float cost = rs * (16.0f * bu + 0.5f * logsum);
    const float aout = 1.0f / (1.0f + __expf(-LAMB * (ba - cost)));

    if (it == iters - 1) {
      if (sub == 0) {
        float4* om = (float4*)(out_mu + (size_t)pos * 512 + c * 16);
        om[0] = make_float4(mu[0],  mu[1],  mu[2],  mu[3]);
        om[1] = make_float4(mu[4],  mu[5],  mu[6],  mu[7]);
        om[2] = make_float4(mu[8],  mu[9],  mu[10], mu[11]);
        om[3] = make_float4(mu[12], mu[13], mu[14], mu[15]);
        out_a[pos * CC + c] = aout;
      }
    } else {
      // ---- E-step: ln_ap into sR. Column c is only touched by this wave
      // (lockstep), so no barrier needed between M reads and these writes.
      const float kc = __logf(aout + EPSF) - 0.5f * logsum - 8.0f * LN2PI;
      for (int k = 0; k < 18; ++k) {
        const int n = sub + 8 * k;
        const float4* Pp = (const float4*)(sP + n * 16);
        const float4 pr[4] = {Pp[0], Pp[1], Pp[2], Pp[3]};
        const float4* Wp = (const float4*)(w + n * 512 + c * 16);
        const float4 wr[4] = {Wp[0], Wp[1], Wp[2], Wp[3]};
        float v[16];
        mat44(pr, wr, v);
        float s = 0.f;
        #pragma unroll
        for (int p = 0; p < 16; ++p) {
          const float d = v[p] - mu[p];
          s = fmaf(d * d, hi[p], s);
        }
        sR[n * RS + c] = kc - s;
      }
      __syncthreads();
      // ---- softmax over classes per n, times a_in -> new r ----
      if (tid < NN) {
        float xv[32];
        float mx = -3.0e38f;
        #pragma unroll
        for (int q = 0; q < 32; ++q) { xv[q] = sR[tid * RS + q]; mx = fmaxf(mx, xv[q]); }
        float ssum = 0.f;
        #pragma unroll
        for (int q = 0; q < 32; ++q) { xv[q] = __expf(xv[q] - mx); ssum += xv[q]; }
        const float sc = sA[tid] / ssum;
        #pragma unroll
        for (int q = 0; q < 32; ++q) sR[tid * RS + q] = xv[q] * sc;
      }
      __syncthreads();
    }
  }
}

} // namespace

extern "C" void kernel_launch(void* const* d_in, const int* in_sizes, int n_in,
                              void* d_out, int out_size, void* d_ws, size_t ws_size,
                              hipStream_t stream) {
  const float* x  = (const float*)d_in[0];
  const float* a  = (const float*)d_in[1];
  const float* w  = (const float*)d_in[2];
  const float* bu = (const float*)d_in[3];
  const float* ba = (const float*)d_in[4];
  const int* iters = (const int*)d_in[5];

  float* out_mu = (float*)d_out;                       // 4*14*14*32*16 = 401408
  float* out_a  = out_mu + (size_t)NPOS * CC * 16;     // + 4*14*14*32  =  25088

  convcaps_em<<<NPOS, 256, 0, stream>>>(x, a, w, bu, ba, iters, out_mu, out_a);
}